// Round 2
// baseline (5887.276 us; speedup 1.0000x reference)
//
#include <hip/hip_runtime.h>
#include <cstdint>
#include <cstddef>

#define MAXDISP 48
#define BATCH   4
#define HH      64
#define WW      128
#define HW      8192

// ---------- bf16 helpers ----------
__device__ __forceinline__ float bf2f(unsigned int u16) {
    union { unsigned int i; float f; } c;
    c.i = u16 << 16;
    return c.f;
}
__device__ __forceinline__ unsigned short f2bf(float f) {
    union { float f; unsigned int i; } c;
    c.f = f;
    unsigned int x = c.i;
    return (unsigned short)((x + 0x7FFFu + ((x >> 16) & 1u)) >> 16);   // RNE
}

// ---------- weight transform: fold BN scale, transpose to [kd][kh][c][kw][co] ----------
__global__ __launch_bounds__(256) void wtrans_kernel(
    const float* __restrict__ wsrc,  // [32][cin][3][3][3]
    const float* __restrict__ gam, const float* __restrict__ bet,
    const float* __restrict__ mea, const float* __restrict__ var,
    float* __restrict__ wt,          // [3][3][cin][3][32]
    float* __restrict__ bias,        // [32]
    int cin)
{
    int n = 32 * cin * 27;
    int idx = blockIdx.x * 256 + threadIdx.x;
    if (idx < n) {
        int co = idx & 31;
        int kw = (idx >> 5) % 3;
        int c  = (idx / 96) % cin;
        int kh = (idx / (96 * cin)) % 3;
        int kd = idx / (288 * cin);
        float inv = gam[co] * rsqrtf(var[co] + 1e-5f);
        wt[idx] = wsrc[(((co * cin + c) * 3 + kd) * 3 + kh) * 3 + kw] * inv;
    }
    if (blockIdx.x == 0 && threadIdx.x < 32) {
        int co = threadIdx.x;
        float inv = gam[co] * rsqrtf(var[co] + 1e-5f);
        bias[co] = bet[co] - mea[co] * inv;
    }
}

// ---------- conv1 with fused cost-volume staging ----------
// Block = (b, global depth gd, h); computes x1[bl][0..32co][l][h][0..128w] (bf16).
// Volume values (corr 0..39, lc 40..51, rc 52..63) are computed on the fly
// from raw inputs during LDS staging — the 201 MB volume is never materialized.
__global__ __launch_bounds__(256) void conv1_fused_kernel(
    const float* __restrict__ lg, const float* __restrict__ rg,
    const float* __restrict__ lc, const float* __restrict__ rc,
    const float* __restrict__ wt,    // [3][3][64][3][32] BN-folded
    const float* __restrict__ bias,  // [32]
    unsigned short* __restrict__ x1, // [nb][32][LS][HW] bf16
    int b_base, int dlo, int ls, int LS)
{
    __shared__ float in_s[64][132];     // volume row at [c][1+w]; pads at 0,129
    __shared__ float wt_s[64][3][32];   // [c][kw][co]

    int bi  = blockIdx.x;
    int h   = bi & (HH - 1);
    int l   = (bi >> 6) % ls;
    int bl  = bi / (ls * HH);
    int b   = b_base + bl;
    int gd  = dlo + l;
    int tid = threadIdx.x;
    int w0  = (tid & 31) * 4;
    int co0 = (tid >> 5) * 4;

    float acc[4][4];
#pragma unroll
    for (int i = 0; i < 4; i++)
#pragma unroll
        for (int j = 0; j < 4; j++) acc[i][j] = 0.f;

    for (int kd = 0; kd < 3; kd++) {
        int dd = gd + kd - 1;
        if (dd < 0 || dd >= MAXDISP) continue;        // block-uniform
        for (int kh = 0; kh < 3; kh++) {
            int hhp = h + kh - 1;
            if (hhp < 0 || hhp >= HH) continue;       // block-uniform

            __syncthreads();
            // ---- stage corr channels [0,40): mean over 8 of lg*rg(shifted) ----
            {
                const float* lbase = lg + (size_t)b * 320 * HW + hhp * WW;
                const float* rbase = rg + (size_t)b * 320 * HW + hhp * WW;
                for (int i = tid; i < 40 * 32; i += 256) {
                    int g  = i >> 5;
                    int w4 = (i & 31) << 2;
                    float s0 = 0.f, s1 = 0.f, s2 = 0.f, s3 = 0.f;
                    if (w4 + 3 >= dd) {
                        const float* lp = lbase + (size_t)(g * 8) * HW + w4;
                        const float* rp = rbase + (size_t)(g * 8) * HW + (w4 - dd);
                        if (w4 >= dd) {
#pragma unroll
                            for (int j = 0; j < 8; j++) {
                                const float4 a = *reinterpret_cast<const float4*>(lp + j * HW);
                                const float* r = rp + j * HW;
                                s0 += a.x * r[0]; s1 += a.y * r[1];
                                s2 += a.z * r[2]; s3 += a.w * r[3];
                            }
                        } else {
#pragma unroll
                            for (int j = 0; j < 8; j++) {
                                const float* lq = lp + j * HW;
                                const float* r  = rp + j * HW;
                                if (w4 + 0 >= dd) s0 += lq[0] * r[0];
                                if (w4 + 1 >= dd) s1 += lq[1] * r[1];
                                if (w4 + 2 >= dd) s2 += lq[2] * r[2];
                                if (w4 + 3 >= dd) s3 += lq[3] * r[3];
                            }
                        }
                        s0 *= 0.125f; s1 *= 0.125f; s2 *= 0.125f; s3 *= 0.125f;
                    }
                    float* dst = &in_s[g][1 + w4];
                    dst[0] = s0; dst[1] = s1; dst[2] = s2; dst[3] = s3;
                }
            }
            // ---- stage concat channels [40,64) ----
            for (int i = tid; i < 24 * 32; i += 256) {
                int k  = i >> 5;
                int w4 = (i & 31) << 2;
                float s0 = 0.f, s1 = 0.f, s2 = 0.f, s3 = 0.f;
                if (k < 12) {
                    const float4 v = *reinterpret_cast<const float4*>(
                        lc + (((size_t)b * 12 + k) * HH + hhp) * WW + w4);
                    s0 = (w4 + 0 >= dd) ? v.x : 0.f;
                    s1 = (w4 + 1 >= dd) ? v.y : 0.f;
                    s2 = (w4 + 2 >= dd) ? v.z : 0.f;
                    s3 = (w4 + 3 >= dd) ? v.w : 0.f;
                } else if (w4 + 3 >= dd) {
                    const float* r = rc + (((size_t)b * 12 + (k - 12)) * HH + hhp) * WW + (w4 - dd);
                    if (w4 >= dd) { s0 = r[0]; s1 = r[1]; s2 = r[2]; s3 = r[3]; }
                    else {
                        if (w4 + 0 >= dd) s0 = r[0];
                        if (w4 + 1 >= dd) s1 = r[1];
                        if (w4 + 2 >= dd) s2 = r[2];
                        if (w4 + 3 >= dd) s3 = r[3];
                    }
                }
                float* dst = &in_s[40 + k][1 + w4];
                dst[0] = s0; dst[1] = s1; dst[2] = s2; dst[3] = s3;
            }
            if (tid < 64) { in_s[tid][0] = 0.f; in_s[tid][129] = 0.f; }
            // ---- stage tap weights ----
            {
                const float* wsrc = wt + (size_t)(kd * 3 + kh) * 64 * 96;
                for (int i = tid * 4; i < 64 * 96; i += 1024) {
                    *reinterpret_cast<float4*>(&wt_s[0][0][0] + i) =
                        *reinterpret_cast<const float4*>(wsrc + i);
                }
            }
            __syncthreads();

            // ---- compute: 4co x 4w register tile ----
#pragma unroll 2
            for (int c = 0; c < 64; c++) {
                float4 i0 = *reinterpret_cast<const float4*>(&in_s[c][w0]);
                float2 i1 = *reinterpret_cast<const float2*>(&in_s[c][w0 + 4]);
                float iv[6] = { i0.x, i0.y, i0.z, i0.w, i1.x, i1.y };
                float4 wk0 = *reinterpret_cast<const float4*>(&wt_s[c][0][co0]);
                float4 wk1 = *reinterpret_cast<const float4*>(&wt_s[c][1][co0]);
                float4 wk2 = *reinterpret_cast<const float4*>(&wt_s[c][2][co0]);
#pragma unroll
                for (int iw = 0; iw < 4; iw++) {
                    float x0 = iv[iw + 0], x1v = iv[iw + 1], x2 = iv[iw + 2];
                    acc[0][iw] += wk0.x * x0; acc[1][iw] += wk0.y * x0;
                    acc[2][iw] += wk0.z * x0; acc[3][iw] += wk0.w * x0;
                    acc[0][iw] += wk1.x * x1v; acc[1][iw] += wk1.y * x1v;
                    acc[2][iw] += wk1.z * x1v; acc[3][iw] += wk1.w * x1v;
                    acc[0][iw] += wk2.x * x2; acc[1][iw] += wk2.y * x2;
                    acc[2][iw] += wk2.z * x2; acc[3][iw] += wk2.w * x2;
                }
            }
        }
    }

    // ---- epilogue: bias + relu, bf16 store into chunk buffer ----
    size_t obase = ((size_t)bl * 32 * LS + l) * HW + h * WW + w0;
#pragma unroll
    for (int ci = 0; ci < 4; ci++) {
        int co = co0 + ci;
        float bs = bias[co];
        float r0 = fmaxf(acc[ci][0] + bs, 0.f);
        float r1 = fmaxf(acc[ci][1] + bs, 0.f);
        float r2 = fmaxf(acc[ci][2] + bs, 0.f);
        float r3 = fmaxf(acc[ci][3] + bs, 0.f);
        ushort4 o = { f2bf(r0), f2bf(r1), f2bf(r2), f2bf(r3) };
        *reinterpret_cast<ushort4*>(x1 + obase + (size_t)co * LS * HW) = o;
    }
}

// ---------- conv2: reads x1 chunk (bf16), writes final fp32 output ----------
__global__ __launch_bounds__(256) void conv2_kernel(
    const unsigned short* __restrict__ x1, // [nb][32][LS][HW]
    const float* __restrict__ wt,          // [3][3][32][3][32]
    const float* __restrict__ bias,
    float* __restrict__ out,               // [B][32][48][64][128] fp32
    int b_base, int d0, int dcnt, int dlo, int LS)
{
    __shared__ float in_s[32][132];
    __shared__ float wt_s[32][3][32];

    int bi  = blockIdx.x;
    int h   = bi & (HH - 1);
    int dl  = (bi >> 6) % dcnt;
    int bl  = bi / (dcnt * HH);
    int b   = b_base + bl;
    int d   = d0 + dl;
    int tid = threadIdx.x;
    int w0  = (tid & 31) * 4;
    int co0 = (tid >> 5) * 4;

    float acc[4][4];
#pragma unroll
    for (int i = 0; i < 4; i++)
#pragma unroll
        for (int j = 0; j < 4; j++) acc[i][j] = 0.f;

    for (int kd = 0; kd < 3; kd++) {
        int dd = d + kd - 1;
        if (dd < 0 || dd >= MAXDISP) continue;
        int l = dd - dlo;                              // within [0, ls)
        for (int kh = 0; kh < 3; kh++) {
            int hhp = h + kh - 1;
            if (hhp < 0 || hhp >= HH) continue;

            __syncthreads();
            const unsigned short* src = x1 + ((size_t)bl * 32 * LS + l) * HW + hhp * WW;
            for (int i = tid * 8; i < 32 * WW; i += 2048) {
                int c = i >> 7;
                int w = i & (WW - 1);
                uint4 raw = *reinterpret_cast<const uint4*>(src + (size_t)c * LS * HW + w);
                float* dst = &in_s[c][w + 1];
                dst[0] = bf2f(raw.x & 0xffffu); dst[1] = bf2f(raw.x >> 16);
                dst[2] = bf2f(raw.y & 0xffffu); dst[3] = bf2f(raw.y >> 16);
                dst[4] = bf2f(raw.z & 0xffffu); dst[5] = bf2f(raw.z >> 16);
                dst[6] = bf2f(raw.w & 0xffffu); dst[7] = bf2f(raw.w >> 16);
            }
            if (tid < 32) { in_s[tid][0] = 0.f; in_s[tid][129] = 0.f; }
            const float* wsrc = wt + (size_t)(kd * 3 + kh) * 32 * 96;
            for (int i = tid * 4; i < 32 * 96; i += 1024) {
                *reinterpret_cast<float4*>(&wt_s[0][0][0] + i) =
                    *reinterpret_cast<const float4*>(wsrc + i);
            }
            __syncthreads();

#pragma unroll 2
            for (int c = 0; c < 32; c++) {
                float4 i0 = *reinterpret_cast<const float4*>(&in_s[c][w0]);
                float2 i1 = *reinterpret_cast<const float2*>(&in_s[c][w0 + 4]);
                float iv[6] = { i0.x, i0.y, i0.z, i0.w, i1.x, i1.y };
                float4 wk0 = *reinterpret_cast<const float4*>(&wt_s[c][0][co0]);
                float4 wk1 = *reinterpret_cast<const float4*>(&wt_s[c][1][co0]);
                float4 wk2 = *reinterpret_cast<const float4*>(&wt_s[c][2][co0]);
#pragma unroll
                for (int iw = 0; iw < 4; iw++) {
                    float x0 = iv[iw + 0], x1v = iv[iw + 1], x2 = iv[iw + 2];
                    acc[0][iw] += wk0.x * x0; acc[1][iw] += wk0.y * x0;
                    acc[2][iw] += wk0.z * x0; acc[3][iw] += wk0.w * x0;
                    acc[0][iw] += wk1.x * x1v; acc[1][iw] += wk1.y * x1v;
                    acc[2][iw] += wk1.z * x1v; acc[3][iw] += wk1.w * x1v;
                    acc[0][iw] += wk2.x * x2; acc[1][iw] += wk2.y * x2;
                    acc[2][iw] += wk2.z * x2; acc[3][iw] += wk2.w * x2;
                }
            }
        }
    }

#pragma unroll
    for (int ci = 0; ci < 4; ci++) {
        int co = co0 + ci;
        float bs = bias[co];
        float4 o;
        o.x = fmaxf(acc[ci][0] + bs, 0.f);
        o.y = fmaxf(acc[ci][1] + bs, 0.f);
        o.z = fmaxf(acc[ci][2] + bs, 0.f);
        o.w = fmaxf(acc[ci][3] + bs, 0.f);
        size_t ob = (((size_t)b * 32 + co) * MAXDISP + d) * HW + h * WW + w0;
        *reinterpret_cast<float4*>(out + ob) = o;
    }
}

extern "C" void kernel_launch(void* const* d_in, const int* in_sizes, int n_in,
                              void* d_out, int out_size, void* d_ws, size_t ws_size,
                              hipStream_t stream)
{
    const float* lg = (const float*)d_in[0];
    const float* rg = (const float*)d_in[1];
    const float* lc = (const float*)d_in[2];
    const float* rc = (const float*)d_in[3];
    const float* w1 = (const float*)d_in[4];
    const float* g1 = (const float*)d_in[5];
    const float* b1 = (const float*)d_in[6];
    const float* m1 = (const float*)d_in[7];
    const float* v1 = (const float*)d_in[8];
    const float* w2 = (const float*)d_in[9];
    const float* g2 = (const float*)d_in[10];
    const float* b2 = (const float*)d_in[11];
    const float* m2 = (const float*)d_in[12];
    const float* v2 = (const float*)d_in[13];
    (void)in_sizes; (void)n_in; (void)out_size;

    // ---- workspace layout (ws_size-adaptive; never exceeds ws_size) ----
    char* ws = (char*)d_ws;
    float* wt1   = (float*)(ws);            // 221,184 B
    float* wt2   = (float*)(ws + 221184);   // 110,592 B
    float* bias1 = (float*)(ws + 331776);   //     128 B
    float* bias2 = (float*)(ws + 331904);   //     128 B
    const size_t WREG = 332288;
    unsigned short* x1 = (unsigned short*)(ws + WREG);

    const size_t slice4 = (size_t)4 * 32 * HW * 2;   // 2 MiB: one depth slice, all 4 batches
    const size_t slice1 = (size_t)32 * HW * 2;       // 512 KiB: one depth slice, one batch
    size_t avail = (ws_size > WREG) ? (ws_size - WREG) : 0;

    int nb, LS;
    if (avail >= 50 * slice4) { nb = 4; LS = 50; }   // whole depth range in one chunk
    else {
        nb = 4; LS = (int)(avail / slice4);
        if (LS < 3) {
            nb = 1; LS = (int)(avail / slice1);
            if (LS < 3) LS = 3;                      // minimum viable; assumes ws >= ~2 MB
        }
        if (LS > 50) LS = 50;
    }
    int cd = LS - 2;
    if (cd > MAXDISP) cd = MAXDISP;

    wtrans_kernel<<<216, 256, 0, stream>>>(w1, g1, b1, m1, v1, wt1, bias1, 64);
    wtrans_kernel<<<108, 256, 0, stream>>>(w2, g2, b2, m2, v2, wt2, bias2, 32);

    for (int b0 = 0; b0 < BATCH; b0 += nb) {
        for (int d0 = 0; d0 < MAXDISP; d0 += cd) {
            int dcnt = (cd < MAXDISP - d0) ? cd : (MAXDISP - d0);
            int dlo  = (d0 - 1 > 0) ? d0 - 1 : 0;
            int dhi  = (d0 + dcnt < MAXDISP) ? d0 + dcnt : MAXDISP - 1;
            int ls   = dhi - dlo + 1;                // <= LS by construction
            conv1_fused_kernel<<<nb * ls * HH, 256, 0, stream>>>(
                lg, rg, lc, rc, wt1, bias1, x1, b0, dlo, ls, LS);
            conv2_kernel<<<nb * dcnt * HH, 256, 0, stream>>>(
                x1, wt2, bias2, (float*)d_out, b0, d0, dcnt, dlo, LS);
        }
    }
}

// Round 3
// 802.549 us; speedup vs baseline: 7.3357x; 7.3357x over previous
//
#include <hip/hip_runtime.h>
#include <cstdint>
#include <cstddef>

typedef unsigned short u16;
typedef __bf16 bf16x8 __attribute__((ext_vector_type(8)));
typedef float f32x4 __attribute__((ext_vector_type(4)));

#define MAXDISP 48
#define HH 64
#define WW 128

// ---------- bf16 helpers ----------
__device__ __forceinline__ float bf2f(unsigned int x) {
    union { unsigned int i; float f; } c; c.i = x << 16; return c.f;
}
__device__ __forceinline__ float bf2f_hi(unsigned int x) {
    union { unsigned int i; float f; } c; c.i = x & 0xffff0000u; return c.f;
}
__device__ __forceinline__ u16 f2bf(float f) {
    union { float f; unsigned int i; } c; c.f = f;
    unsigned int x = c.i;
    return (u16)((x + 0x7fffu + ((x >> 16) & 1u)) >> 16);   // RNE
}

// ---------- weight transform: BN-fold + swizzle into MFMA B-fragment order ----------
// dst[tap][nt][kc][lane][j] bf16, tap=kd*3+kh, co=nt*16+(lane&15),
// k-chunk kc: CIN=64: kw=kc>>1, c=(kc&1)*32+(lane>>4)*8+j ; CIN=32: kw=kc, c=(lane>>4)*8+j
__global__ __launch_bounds__(256) void wfrag_kernel(
    const float* __restrict__ w, const float* __restrict__ gam,
    const float* __restrict__ bet, const float* __restrict__ mea,
    const float* __restrict__ var,
    u16* __restrict__ dst, float* __restrict__ bias, int CIN, int KC)
{
    int idx = blockIdx.x * 256 + threadIdx.x;
    int n = 9 * 2 * KC * 512;
    if (idx < n) {
        int j    = idx & 7;
        int lane = (idx >> 3) & 63;
        int t2   = idx >> 9;
        int kc   = t2 % KC;
        int t3   = t2 / KC;
        int nt   = t3 & 1;
        int tap  = t3 >> 1;
        int co   = nt * 16 + (lane & 15);
        int qq   = lane >> 4;
        int kw, c;
        if (CIN == 64) { kw = kc >> 1; c = (kc & 1) * 32 + qq * 8 + j; }
        else           { kw = kc;      c = qq * 8 + j; }
        int kd = tap / 3, kh = tap % 3;
        float inv = gam[co] * rsqrtf(var[co] + 1e-5f);
        dst[idx] = f2bf(w[((size_t)co * CIN + c) * 27 + kd * 9 + kh * 3 + kw] * inv);
    }
    if (blockIdx.x == 0 && threadIdx.x < 32) {
        int co = threadIdx.x;
        float inv = gam[co] * rsqrtf(var[co] + 1e-5f);
        bias[co] = bet[co] - mea[co] * inv;
    }
}

// ---------- cost volume, channel-last: vol[bl][d][h][w][c64] bf16 ----------
// block = (bl, dhalf, h); rg+rc staged transposed [w][c] bf16 in LDS; corr
// computed from fp32 lg (registers) x bf16 rg (LDS); out slab per 4 d.
#define RS 334   // r_s row stride (u16): stride/2 odd -> 2-way-free b32 reads
__global__ __launch_bounds__(256) void vol_build_kernel(
    const float* __restrict__ lg, const float* __restrict__ rg,
    const float* __restrict__ lc, const float* __restrict__ rc,
    u16* __restrict__ vol, int b0)
{
    __shared__ u16 r_s[128 * RS];       // [w][0..319 rg | 320..331 rc]
    __shared__ u16 o_s[4 * 128 * 68];   // [dl][w][c64 +4 pad]

    int bi  = blockIdx.x;               // bl*128 + dh*64 + h
    int h   = bi & 63;
    int dh  = (bi >> 6) & 1;
    int bl  = bi >> 7;
    int b   = b0 + bl;
    int tid = threadIdx.x;
    int w    = tid & 127;
    int part = tid >> 7;

    for (int idx = tid; idx < 320 * 32; idx += 256) {
        int c = idx >> 5, w4 = (idx & 31) << 2;
        const float4 v = *(const float4*)(rg + (((size_t)b * 320 + c) * 64 + h) * 128 + w4);
        r_s[(w4 + 0) * RS + c] = f2bf(v.x);
        r_s[(w4 + 1) * RS + c] = f2bf(v.y);
        r_s[(w4 + 2) * RS + c] = f2bf(v.z);
        r_s[(w4 + 3) * RS + c] = f2bf(v.w);
    }
    for (int idx = tid; idx < 12 * 32; idx += 256) {
        int c = idx >> 5, w4 = (idx & 31) << 2;
        const float4 v = *(const float4*)(rc + (((size_t)b * 12 + c) * 64 + h) * 128 + w4);
        r_s[(w4 + 0) * RS + 320 + c] = f2bf(v.x);
        r_s[(w4 + 1) * RS + 320 + c] = f2bf(v.y);
        r_s[(w4 + 2) * RS + 320 + c] = f2bf(v.z);
        r_s[(w4 + 3) * RS + 320 + c] = f2bf(v.w);
    }
    u16 lcv[12];
    if (part == 0) {
#pragma unroll
        for (int k = 0; k < 12; k++)
            lcv[k] = f2bf(lc[(((size_t)b * 12 + k) * 64 + h) * 128 + w]);
    }
    __syncthreads();

    int d0 = dh * 24;
    for (int dc = 0; dc < 24; dc += 4) {
        // ---- corr channels: part0 g 0..19, part1 g 20..39 ----
        for (int gb = 0; gb < 5; gb++) {
            int g0 = part * 20 + gb * 4;
            float lv[4][8];
#pragma unroll
            for (int gg = 0; gg < 4; gg++)
#pragma unroll
                for (int j = 0; j < 8; j++)
                    lv[gg][j] = lg[(((size_t)b * 320 + (g0 + gg) * 8 + j) * 64 + h) * 128 + w];
#pragma unroll
            for (int dl = 0; dl < 4; dl++) {
                int d = d0 + dc + dl;
                union { u16 us[4]; uint2 u2; } pk;
                pk.us[0] = pk.us[1] = pk.us[2] = pk.us[3] = 0;
                if (w >= d) {
#pragma unroll
                    for (int gg = 0; gg < 4; gg++) {
                        float s = 0.f;
                        int base = (w - d) * RS + (g0 + gg) * 8;
#pragma unroll
                        for (int jj = 0; jj < 4; jj++) {
                            unsigned int uu = *(const unsigned int*)&r_s[base + jj * 2];
                            s += lv[gg][jj * 2]     * bf2f(uu & 0xffffu);
                            s += lv[gg][jj * 2 + 1] * bf2f_hi(uu);
                        }
                        pk.us[gg] = f2bf(s * 0.125f);
                    }
                }
                *(uint2*)&o_s[(dl * 128 + w) * 68 + g0] = pk.u2;
            }
        }
        // ---- concat channels ----
#pragma unroll
        for (int dl = 0; dl < 4; dl++) {
            int d = d0 + dc + dl;
            union { u16 us[12]; uint2 u2[3]; } z;
            if (part == 0) {
#pragma unroll
                for (int k = 0; k < 12; k++) z.us[k] = (w >= d) ? lcv[k] : (u16)0;
                u16* dst = &o_s[(dl * 128 + w) * 68 + 40];
                *(uint2*)(dst + 0) = z.u2[0];
                *(uint2*)(dst + 4) = z.u2[1];
                *(uint2*)(dst + 8) = z.u2[2];
            } else {
                if (w >= d) {
                    int base = (w - d) * RS + 320;
#pragma unroll
                    for (int k = 0; k < 12; k++) z.us[k] = r_s[base + k];
                } else {
#pragma unroll
                    for (int k = 0; k < 12; k++) z.us[k] = 0;
                }
                u16* dst = &o_s[(dl * 128 + w) * 68 + 52];
                *(uint2*)(dst + 0) = z.u2[0];
                *(uint2*)(dst + 4) = z.u2[1];
                *(uint2*)(dst + 8) = z.u2[2];
            }
        }
        __syncthreads();
        // ---- flush 4 d-slabs, coalesced ----
#pragma unroll
        for (int i = 0; i < 16; i++) {
            int idx = i * 256 + tid;            // [0,4096)
            int dl  = idx >> 10;
            int rem = idx & 1023;
            int ww  = rem >> 3, cg = rem & 7;
            const u16* sp = &o_s[(dl * 128 + ww) * 68 + cg * 8];
            uint2 lo = *(const uint2*)sp;
            uint2 hi = *(const uint2*)(sp + 4);
            uint4 ov = { lo.x, lo.y, hi.x, hi.y };
            int d = d0 + dc + dl;
            *(uint4*)(vol + ((((size_t)bl * 48 + d) * 64 + h) * 128 + ww) * 64 + cg * 8) = ov;
        }
        __syncthreads();
    }
}

// ---------- conv1: implicit-GEMM MFMA, vol[bl][d][h][w][c64] -> x1[bl][d][h][w][c32] ----------
__global__ __launch_bounds__(256) void conv1_mfma_kernel(
    const u16* __restrict__ vol, const u16* __restrict__ wf,
    const float* __restrict__ bias, u16* __restrict__ x1)
{
    __shared__ u16 a_s[1170 * 8];   // chunk (wp*9+cg), wp in [0,130), cg in [0,8)

    int bi = blockIdx.x;            // (bl*48 + d)*64 + h
    int h  = bi & 63;
    int t1 = bi >> 6;
    int d  = t1 % 48;
    int bl = t1 / 48;
    int tid  = threadIdx.x;
    int lane = tid & 63, wid = tid >> 6;
    int lm = lane & 15, q = lane >> 4;

    f32x4 acc[2][2];
#pragma unroll
    for (int i = 0; i < 2; i++)
#pragma unroll
        for (int j = 0; j < 2; j++) acc[i][j] = { 0.f, 0.f, 0.f, 0.f };

    for (int kd = 0; kd < 3; kd++) {
        int dd = d + kd - 1;
        if (dd < 0 || dd >= 48) continue;
        for (int kh = 0; kh < 3; kh++) {
            int hh = h + kh - 1;
            if (hh < 0 || hh >= 64) continue;
            int tap = kd * 3 + kh;

            __syncthreads();
            const u16* src = vol + (((size_t)bl * 48 + dd) * 64 + hh) * 8192;
#pragma unroll
            for (int i = 0; i < 4; i++) {
                int idx = i * 256 + tid;            // [0,1024)
                int wp = (idx >> 3) + 1, cg = idx & 7;
                uint4 v = *(const uint4*)(src + idx * 8);
                *(uint4*)&a_s[(wp * 9 + cg) * 8] = v;
            }
            if (tid < 16) {
                uint4 z = { 0, 0, 0, 0 };
                int wp = (tid >> 3) ? 129 : 0;
                *(uint4*)&a_s[(wp * 9 + (tid & 7)) * 8] = z;
            }
            __syncthreads();

            bf16x8 bfr[2][6];
#pragma unroll
            for (int nt = 0; nt < 2; nt++)
#pragma unroll
                for (int kc = 0; kc < 6; kc++)
                    bfr[nt][kc] = *(const bf16x8*)(wf + (((size_t)tap * 2 + nt) * 6 + kc) * 512 + lane * 8);

#pragma unroll
            for (int kc = 0; kc < 6; kc++) {
                int kw = kc >> 1;
                int cg = (kc & 1) * 4 + q;
#pragma unroll
                for (int mt = 0; mt < 2; mt++) {
                    int wp = (wid * 2 + mt) * 16 + lm + kw;
                    bf16x8 afr = *(const bf16x8*)&a_s[(wp * 9 + cg) * 8];
                    acc[mt][0] = __builtin_amdgcn_mfma_f32_16x16x32_bf16(afr, bfr[0][kc], acc[mt][0], 0, 0, 0);
                    acc[mt][1] = __builtin_amdgcn_mfma_f32_16x16x32_bf16(afr, bfr[1][kc], acc[mt][1], 0, 0, 0);
                }
            }
        }
    }

    // epilogue: D row=(lane>>4)*4+reg = w-offset, col=lane&15 = co-offset
    u16* xb = x1 + (((size_t)bl * 48 + d) * 64 + h) * 4096;
#pragma unroll
    for (int mt = 0; mt < 2; mt++)
#pragma unroll
        for (int nt = 0; nt < 2; nt++) {
            int co = nt * 16 + lm;
            float bs = bias[co];
#pragma unroll
            for (int r = 0; r < 4; r++) {
                int w = (wid * 2 + mt) * 16 + q * 4 + r;
                xb[w * 32 + co] = f2bf(fmaxf(acc[mt][nt][r] + bs, 0.f));
            }
        }
}

// ---------- conv2: implicit-GEMM MFMA, x1 -> out fp32 [b][co][d][h][w] ----------
__global__ __launch_bounds__(256) void conv2_mfma_kernel(
    const u16* __restrict__ x1, const u16* __restrict__ wf,
    const float* __restrict__ bias, float* __restrict__ out, int b0)
{
    __shared__ u16 a_s[650 * 8];    // chunk (wp*5+cg), wp in [0,130), cg in [0,4)

    int bi = blockIdx.x;
    int h  = bi & 63;
    int t1 = bi >> 6;
    int d  = t1 % 48;
    int bl = t1 / 48;
    int tid  = threadIdx.x;
    int lane = tid & 63, wid = tid >> 6;
    int lm = lane & 15, q = lane >> 4;

    f32x4 acc[2][2];
#pragma unroll
    for (int i = 0; i < 2; i++)
#pragma unroll
        for (int j = 0; j < 2; j++) acc[i][j] = { 0.f, 0.f, 0.f, 0.f };

    for (int kd = 0; kd < 3; kd++) {
        int dd = d + kd - 1;
        if (dd < 0 || dd >= 48) continue;
        for (int kh = 0; kh < 3; kh++) {
            int hh = h + kh - 1;
            if (hh < 0 || hh >= 64) continue;
            int tap = kd * 3 + kh;

            __syncthreads();
            const u16* src = x1 + (((size_t)bl * 48 + dd) * 64 + hh) * 4096;
#pragma unroll
            for (int i = 0; i < 2; i++) {
                int idx = i * 256 + tid;            // [0,512)
                int wp = (idx >> 2) + 1, cg = idx & 3;
                uint4 v = *(const uint4*)(src + idx * 8);
                *(uint4*)&a_s[(wp * 5 + cg) * 8] = v;
            }
            if (tid < 8) {
                uint4 z = { 0, 0, 0, 0 };
                int wp = (tid >> 2) ? 129 : 0;
                *(uint4*)&a_s[(wp * 5 + (tid & 3)) * 8] = z;
            }
            __syncthreads();

            bf16x8 bfr[2][3];
#pragma unroll
            for (int nt = 0; nt < 2; nt++)
#pragma unroll
                for (int kc = 0; kc < 3; kc++)
                    bfr[nt][kc] = *(const bf16x8*)(wf + (((size_t)tap * 2 + nt) * 3 + kc) * 512 + lane * 8);

#pragma unroll
            for (int kc = 0; kc < 3; kc++) {
                int kw = kc;
#pragma unroll
                for (int mt = 0; mt < 2; mt++) {
                    int wp = (wid * 2 + mt) * 16 + lm + kw;
                    bf16x8 afr = *(const bf16x8*)&a_s[(wp * 5 + q) * 8];
                    acc[mt][0] = __builtin_amdgcn_mfma_f32_16x16x32_bf16(afr, bfr[0][kc], acc[mt][0], 0, 0, 0);
                    acc[mt][1] = __builtin_amdgcn_mfma_f32_16x16x32_bf16(afr, bfr[1][kc], acc[mt][1], 0, 0, 0);
                }
            }
        }
    }

#pragma unroll
    for (int mt = 0; mt < 2; mt++)
#pragma unroll
        for (int nt = 0; nt < 2; nt++) {
            int co = nt * 16 + lm;
            float bs = bias[co];
            float4 o;
            o.x = fmaxf(acc[mt][nt][0] + bs, 0.f);
            o.y = fmaxf(acc[mt][nt][1] + bs, 0.f);
            o.z = fmaxf(acc[mt][nt][2] + bs, 0.f);
            o.w = fmaxf(acc[mt][nt][3] + bs, 0.f);
            int wbase = (wid * 2 + mt) * 16 + q * 4;
            *(float4*)(out + ((((size_t)(b0 + bl) * 32 + co) * 48 + d) * 64 + h) * 128 + wbase) = o;
        }
}

extern "C" void kernel_launch(void* const* d_in, const int* in_sizes, int n_in,
                              void* d_out, int out_size, void* d_ws, size_t ws_size,
                              hipStream_t stream)
{
    const float* lg = (const float*)d_in[0];
    const float* rg = (const float*)d_in[1];
    const float* lc = (const float*)d_in[2];
    const float* rc = (const float*)d_in[3];
    const float* w1 = (const float*)d_in[4];
    const float* g1 = (const float*)d_in[5];
    const float* b1 = (const float*)d_in[6];
    const float* m1 = (const float*)d_in[7];
    const float* v1 = (const float*)d_in[8];
    const float* w2 = (const float*)d_in[9];
    const float* g2 = (const float*)d_in[10];
    const float* b2 = (const float*)d_in[11];
    const float* m2 = (const float*)d_in[12];
    const float* v2 = (const float*)d_in[13];
    (void)in_sizes; (void)n_in; (void)out_size; (void)ws_size;

    // ws layout (total ~50.5 MB << 96 MiB observed ws_size):
    char* ws = (char*)d_ws;
    u16*   wf1   = (u16*)ws;                 // 110,592 B
    u16*   wf2   = (u16*)(ws + 110592);      //  55,296 B
    float* bias1 = (float*)(ws + 165888);    //     128 B
    float* bias2 = (float*)(ws + 166016);    //     128 B
    u16*   x1    = (u16*)(ws + 166144);      // 50,331,648 B  [2][48][64][128][32] bf16

    wfrag_kernel<<<216, 256, 0, stream>>>(w1, g1, b1, m1, v1, wf1, bias1, 64, 6);
    wfrag_kernel<<<108, 256, 0, stream>>>(w2, g2, b2, m2, v2, wf2, bias2, 32, 3);

    // Per batch-pair: vol lives in the d_out region that this pair's conv2
    // output will overwrite (vol is dead by then; regions are byte-identical).
    for (int r = 0; r < 2; r++) {
        u16* vol = (u16*)d_out + (size_t)r * 50331648;   // [2][48][64][128][64] bf16
        vol_build_kernel<<<256, 256, 0, stream>>>(lg, rg, lc, rc, vol, 2 * r);
        conv1_mfma_kernel<<<6144, 256, 0, stream>>>(vol, wf1, bias1, x1);
        conv2_mfma_kernel<<<6144, 256, 0, stream>>>(x1, wf2, bias2, (float*)d_out, 2 * r);
    }
}